// Round 1
// baseline (740.560 us; speedup 1.0000x reference)
//
#include <hip/hip_runtime.h>
#include <math.h>

#define NB 16
#define PP 1024
#define DD 64
#define MAX_ITER 10

constexpr float EPSV     = 0.1f;
constexpr float INV_EPS  = 10.0f;
constexpr float LOG2E    = 1.44269504088896340736f;
constexpr float LOG_MU   = -6.93146156597137f;   // log(1/1024 + 1e-8)
constexpr float THRESHV  = 0.1f;

// ---------------------------------------------------------------------------
// Cs[n][i][j] = |x_i - y_j|^2 / eps   (stored in d_out; overwritten by pi later)
// block = 256 threads; each block: one n, one 64-row i-tile, all 1024 j.
// Block 0 additionally zero-inits a, b, doneArr (fresh state every call).
// ---------------------------------------------------------------------------
__global__ __launch_bounds__(256) void compute_c(
    const float* __restrict__ x, const float* __restrict__ y,
    float* __restrict__ Cs, float* __restrict__ a, float* __restrict__ b,
    int* __restrict__ doneArr)
{
  const int bid = blockIdx.x;
  const int n   = bid >> 4;
  const int ib  = bid & 15;

  if (bid == 0) {
    for (int t = threadIdx.x; t < NB * PP; t += 256) { a[t] = 0.f; b[t] = 0.f; }
    if (threadIdx.x < 16) doneArr[threadIdx.x] = 0;
  }

  __shared__ float xs[64][68];   // [i][d], stride 68 keeps 16B-aligned rows, 2-way-max banks
  __shared__ float ys[64][68];   // [j][d]

  const float* xb = x + ((size_t)n * PP + ib * 64) * DD;
  const float* yb = y + (size_t)n * PP * DD;

  // load x tile (64 rows x 64 d), float4-vectorized, coalesced
  for (int t = threadIdx.x; t < 64 * 16; t += 256) {
    int r = t >> 4, d4 = (t & 15) * 4;
    float4 v = *(const float4*)(xb + r * DD + d4);
    xs[r][d4] = v.x; xs[r][d4 + 1] = v.y; xs[r][d4 + 2] = v.z; xs[r][d4 + 3] = v.w;
  }

  const int tx = threadIdx.x & 15;       // j-group: cols {tx, tx+16, tx+32, tx+48}
  const int ty = threadIdx.x >> 4;       // i-group: rows i0..i0+3
  const int i0 = ty * 4;
  float* outb = Cs + ((size_t)n * PP + ib * 64) * PP;

  for (int jt = 0; jt < 16; ++jt) {
    __syncthreads();   // protect previous ys readers (and first-iter xs writes)
    for (int t = threadIdx.x; t < 64 * 16; t += 256) {
      int r = t >> 4, d4 = (t & 15) * 4;
      float4 v = *(const float4*)(yb + ((size_t)(jt * 64 + r)) * DD + d4);
      ys[r][d4] = v.x; ys[r][d4 + 1] = v.y; ys[r][d4 + 2] = v.z; ys[r][d4 + 3] = v.w;
    }
    __syncthreads();

    float acc[4][4] = {};
    for (int d0 = 0; d0 < 64; d0 += 4) {
      float4 xv[4], yv[4];
      #pragma unroll
      for (int ii = 0; ii < 4; ++ii) xv[ii] = *(const float4*)&xs[i0 + ii][d0];
      #pragma unroll
      for (int jj = 0; jj < 4; ++jj) yv[jj] = *(const float4*)&ys[tx + 16 * jj][d0];
      #pragma unroll
      for (int ii = 0; ii < 4; ++ii) {
        #pragma unroll
        for (int jj = 0; jj < 4; ++jj) {
          float d;
          d = xv[ii].x - yv[jj].x; acc[ii][jj] = fmaf(d, d, acc[ii][jj]);
          d = xv[ii].y - yv[jj].y; acc[ii][jj] = fmaf(d, d, acc[ii][jj]);
          d = xv[ii].z - yv[jj].z; acc[ii][jj] = fmaf(d, d, acc[ii][jj]);
          d = xv[ii].w - yv[jj].w; acc[ii][jj] = fmaf(d, d, acc[ii][jj]);
        }
      }
    }
    #pragma unroll
    for (int ii = 0; ii < 4; ++ii)
      #pragma unroll
      for (int jj = 0; jj < 4; ++jj)
        outb[(size_t)(i0 + ii) * PP + jt * 64 + tx + 16 * jj] = acc[ii][jj] * INV_EPS;
  }
}

// ---------------------------------------------------------------------------
// U half-iteration: a_i = LOG_MU - lse_j(b_j - Cs_ij).  One wave per row.
// Also records |delta a| per row for the convergence test.
// ---------------------------------------------------------------------------
__global__ __launch_bounds__(256) void u_kernel(
    const float* __restrict__ Cs, float* __restrict__ a, const float* __restrict__ b,
    float* __restrict__ err_rows, const int* __restrict__ doneArr, int it)
{
  if (doneArr[it]) return;   // frozen: keep a unchanged
  const int lane = threadIdx.x & 63;
  const int row  = (blockIdx.x << 2) + (threadIdx.x >> 6);
  const int n    = row >> 10;
  const float* crow = Cs + (size_t)row * PP;
  const float* bn   = b + n * PP;

  float vals[16];
  float m = -INFINITY;
  #pragma unroll
  for (int kk = 0; kk < 4; ++kk) {
    float4 c4 = *(const float4*)(crow + lane * 4 + kk * 256);
    float4 b4 = *(const float4*)(bn   + lane * 4 + kk * 256);
    float t0 = b4.x - c4.x, t1 = b4.y - c4.y, t2 = b4.z - c4.z, t3 = b4.w - c4.w;
    vals[4*kk+0] = t0; vals[4*kk+1] = t1; vals[4*kk+2] = t2; vals[4*kk+3] = t3;
    m = fmaxf(m, fmaxf(fmaxf(t0, t1), fmaxf(t2, t3)));
  }
  #pragma unroll
  for (int off = 32; off > 0; off >>= 1) m = fmaxf(m, __shfl_xor(m, off));
  float s = 0.f;
  #pragma unroll
  for (int t = 0; t < 16; ++t) s += exp2f((vals[t] - m) * LOG2E);
  #pragma unroll
  for (int off = 32; off > 0; off >>= 1) s += __shfl_xor(s, off);
  if (lane == 0) {
    float an = LOG_MU - (m + logf(s));
    float delta = fabsf(an - a[row]);
    a[row] = an;
    err_rows[row] = delta;
  }
}

// ---------------------------------------------------------------------------
// V half-iteration: b_j = LOG_NU - lse_i(a_i - Cs_ij).  Column reduction.
// Block = 32-column stripe of one batch; two-pass (max, exp-sum); pass 2 hits L2.
// Block 0 then reduces err_rows deterministically and sets doneArr[it+1].
// ---------------------------------------------------------------------------
__global__ __launch_bounds__(256) void v_kernel(
    const float* __restrict__ Cs, const float* __restrict__ a, float* __restrict__ b,
    const float* __restrict__ err_rows, int* __restrict__ doneArr, int it)
{
  if (doneArr[it]) {
    if (blockIdx.x == 0 && threadIdx.x == 0) doneArr[it + 1] = 1;  // stays done
    return;
  }
  __shared__ float as[PP];
  __shared__ float red[8][33];

  const int n  = blockIdx.x >> 5;
  const int jt = blockIdx.x & 31;
  const float* an = a + n * PP;
  for (int t = threadIdx.x; t < PP; t += 256) as[t] = an[t];
  __syncthreads();

  const int tx = threadIdx.x & 31;   // column within stripe
  const int ty = threadIdx.x >> 5;   // row phase (stride 8)
  const float* cb = Cs + (size_t)n * PP * PP + jt * 32 + tx;

  float m = -INFINITY;
  #pragma unroll 8
  for (int i = ty; i < PP; i += 8)
    m = fmaxf(m, as[i] - cb[(size_t)i * PP]);

  red[ty][tx] = m;
  __syncthreads();
  if (ty == 0) {
    #pragma unroll
    for (int k = 1; k < 8; ++k) m = fmaxf(m, red[k][tx]);
    red[0][tx] = m;
  }
  __syncthreads();
  m = red[0][tx];

  float s = 0.f;
  #pragma unroll 8
  for (int i = ty; i < PP; i += 8)
    s += exp2f((as[i] - cb[(size_t)i * PP] - m) * LOG2E);

  __syncthreads();             // everyone has read red[0][tx]
  red[ty][tx] = s;
  __syncthreads();
  if (ty == 0) {
    #pragma unroll
    for (int k = 1; k < 8; ++k) s += red[k][tx];
    b[n * PP + jt * 32 + tx] = LOG_MU - (m + logf(s));
  }

  // --- convergence flag (deterministic fixed-order reduction) ---
  if (blockIdx.x == 0) {
    __syncthreads();
    float loc = 0.f;
    for (int t = threadIdx.x; t < NB * PP; t += 256) loc += err_rows[t];
    #pragma unroll
    for (int off = 32; off > 0; off >>= 1) loc += __shfl_xor(loc, off);
    if ((threadIdx.x & 63) == 0) red[0][threadIdx.x >> 6] = loc;
    __syncthreads();
    if (threadIdx.x == 0) {
      float tot = red[0][0] + red[0][1] + red[0][2] + red[0][3];
      float err = tot * (EPSV / (float)NB);   // err = eps * sum|da| / N
      doneArr[it + 1] = (err < THRESHV) ? 1 : 0;
    }
  }
}

// ---------------------------------------------------------------------------
// pi = exp(a_i + b_j - Cs_ij), in place over Cs (which lives in d_out).
// ---------------------------------------------------------------------------
__global__ __launch_bounds__(256) void pi_kernel(
    float* __restrict__ Cs, const float* __restrict__ a, const float* __restrict__ b)
{
  const int lane = threadIdx.x & 63;
  const int row  = (blockIdx.x << 2) + (threadIdx.x >> 6);
  const int n    = row >> 10;
  const float ai = a[row];
  float* crow = Cs + (size_t)row * PP;
  const float* bn = b + n * PP;
  #pragma unroll
  for (int kk = 0; kk < 4; ++kk) {
    float4 c4 = *(const float4*)(crow + lane * 4 + kk * 256);
    float4 b4 = *(const float4*)(bn   + lane * 4 + kk * 256);
    float4 r;
    r.x = exp2f((ai + b4.x - c4.x) * LOG2E);
    r.y = exp2f((ai + b4.y - c4.y) * LOG2E);
    r.z = exp2f((ai + b4.z - c4.z) * LOG2E);
    r.w = exp2f((ai + b4.w - c4.w) * LOG2E);
    *(float4*)(crow + lane * 4 + kk * 256) = r;
  }
}

extern "C" void kernel_launch(void* const* d_in, const int* in_sizes, int n_in,
                              void* d_out, int out_size, void* d_ws, size_t ws_size,
                              hipStream_t stream)
{
  const float* y = (const float*)d_in[0];   // setup_inputs order: y first!
  const float* x = (const float*)d_in[1];

  float* Cs       = (float*)d_out;          // 16M floats: cost matrix, later pi in-place
  float* a        = (float*)d_ws;           // 16K floats (scaled dual u/eps)
  float* b        = a + NB * PP;            // 16K floats (scaled dual v/eps)
  float* err_rows = b + NB * PP;            // 16K floats |delta a|
  int*   doneArr  = (int*)(err_rows + NB * PP);  // 16 ints, doneArr[it] = converged before iter it

  compute_c<<<NB * 16, 256, 0, stream>>>(x, y, Cs, a, b, doneArr);
  for (int it = 0; it < MAX_ITER; ++it) {
    u_kernel<<<NB * PP / 4, 256, 0, stream>>>(Cs, a, b, err_rows, doneArr, it);
    v_kernel<<<NB * 32,     256, 0, stream>>>(Cs, a, b, err_rows, doneArr, it);
  }
  pi_kernel<<<NB * PP / 4, 256, 0, stream>>>(Cs, a, b);
}

// Round 2
// 570.354 us; speedup vs baseline: 1.2984x; 1.2984x over previous
//
#include <hip/hip_runtime.h>
#include <math.h>

#define NB 16
#define PP 1024
#define DD 64
#define MAX_ITER 10
#define RCHUNK 16                 // rows per v-partial block
#define NCHUNK (PP / RCHUNK)      // 64 chunks per batch

constexpr float EPSV    = 0.1f;
constexpr float INV_EPS = 10.0f;
constexpr float LOG2E   = 1.44269504088896340736f;
constexpr float LOG_MU  = -6.93146156597137f;   // log(1/1024 + 1e-8)
constexpr float THRESHV = 0.1f;

// ---------------------------------------------------------------------------
// Cs[n][i][j] = |x_i - y_j|^2 / eps  (into d_out; later overwritten by pi)
// Grid 2048: n(16) x itile(16, 64 rows) x jtile(8, 128 cols). 52KB LDS -> 3 blk/CU.
// Block 0 also zero-inits a, b, doneArr (fresh state every call).
// ---------------------------------------------------------------------------
__global__ __launch_bounds__(256) void compute_c(
    const float* __restrict__ x, const float* __restrict__ y,
    float* __restrict__ Cs, float* __restrict__ a, float* __restrict__ b,
    int* __restrict__ doneArr)
{
  const int bid = blockIdx.x;
  const int n   = bid >> 7;
  const int ib  = (bid >> 3) & 15;
  const int jb  = bid & 7;

  if (bid == 0) {
    for (int t = threadIdx.x; t < NB * PP; t += 256) { a[t] = 0.f; b[t] = 0.f; }
    if (threadIdx.x < 16) doneArr[threadIdx.x] = 0;
  }

  __shared__ float xs[64][68];    // stride 68: float4-aligned, conflict-light
  __shared__ float ys[128][68];

  const float* xb = x + ((size_t)n * PP + ib * 64) * DD;
  const float* yb = y + ((size_t)n * PP + jb * 128) * DD;

  for (int t = threadIdx.x; t < 64 * 16; t += 256) {
    int r = t >> 4, d4 = (t & 15) * 4;
    float4 v = *(const float4*)(xb + r * DD + d4);
    xs[r][d4] = v.x; xs[r][d4 + 1] = v.y; xs[r][d4 + 2] = v.z; xs[r][d4 + 3] = v.w;
  }
  for (int t = threadIdx.x; t < 128 * 16; t += 256) {
    int r = t >> 4, d4 = (t & 15) * 4;
    float4 v = *(const float4*)(yb + (size_t)r * DD + d4);
    ys[r][d4] = v.x; ys[r][d4 + 1] = v.y; ys[r][d4 + 2] = v.z; ys[r][d4 + 3] = v.w;
  }
  __syncthreads();

  const int tx = threadIdx.x & 15;   // j: cols tx + 16*jj, jj=0..7
  const int ty = threadIdx.x >> 4;   // i: rows 4*ty .. 4*ty+3
  const int i0 = ty * 4;

  float acc[4][8] = {};
  for (int d0 = 0; d0 < 64; d0 += 4) {
    float4 xv[4], yv[8];
    #pragma unroll
    for (int ii = 0; ii < 4; ++ii) xv[ii] = *(const float4*)&xs[i0 + ii][d0];
    #pragma unroll
    for (int jj = 0; jj < 8; ++jj) yv[jj] = *(const float4*)&ys[tx + 16 * jj][d0];
    #pragma unroll
    for (int ii = 0; ii < 4; ++ii) {
      #pragma unroll
      for (int jj = 0; jj < 8; ++jj) {
        float d;
        d = xv[ii].x - yv[jj].x; acc[ii][jj] = fmaf(d, d, acc[ii][jj]);
        d = xv[ii].y - yv[jj].y; acc[ii][jj] = fmaf(d, d, acc[ii][jj]);
        d = xv[ii].z - yv[jj].z; acc[ii][jj] = fmaf(d, d, acc[ii][jj]);
        d = xv[ii].w - yv[jj].w; acc[ii][jj] = fmaf(d, d, acc[ii][jj]);
      }
    }
  }

  float* outb = Cs + ((size_t)n * PP + ib * 64) * PP + jb * 128;
  #pragma unroll
  for (int ii = 0; ii < 4; ++ii)
    #pragma unroll
    for (int jj = 0; jj < 8; ++jj)
      outb[(size_t)(i0 + ii) * PP + tx + 16 * jj] = acc[ii][jj] * INV_EPS;
}

// ---------------------------------------------------------------------------
// U half-iteration: a_i = LOG_MU - lse_j(b_j - Cs_ij). One wave per row.
// ---------------------------------------------------------------------------
__global__ __launch_bounds__(256) void u_kernel(
    const float* __restrict__ Cs, float* __restrict__ a, const float* __restrict__ b,
    float* __restrict__ err_rows, const int* __restrict__ doneArr, int it)
{
  if (doneArr[it]) return;
  const int lane = threadIdx.x & 63;
  const int row  = (blockIdx.x << 2) + (threadIdx.x >> 6);
  const int n    = row >> 10;
  const float* crow = Cs + (size_t)row * PP;
  const float* bn   = b + n * PP;

  float vals[16];
  float m = -INFINITY;
  #pragma unroll
  for (int kk = 0; kk < 4; ++kk) {
    float4 c4 = *(const float4*)(crow + lane * 4 + kk * 256);
    float4 b4 = *(const float4*)(bn   + lane * 4 + kk * 256);
    float t0 = b4.x - c4.x, t1 = b4.y - c4.y, t2 = b4.z - c4.z, t3 = b4.w - c4.w;
    vals[4*kk+0] = t0; vals[4*kk+1] = t1; vals[4*kk+2] = t2; vals[4*kk+3] = t3;
    m = fmaxf(m, fmaxf(fmaxf(t0, t1), fmaxf(t2, t3)));
  }
  #pragma unroll
  for (int off = 32; off > 0; off >>= 1) m = fmaxf(m, __shfl_xor(m, off));
  float s = 0.f;
  #pragma unroll
  for (int t = 0; t < 16; ++t) s += exp2f((vals[t] - m) * LOG2E);
  #pragma unroll
  for (int off = 32; off > 0; off >>= 1) s += __shfl_xor(s, off);
  if (lane == 0) {
    float an = LOG_MU - (m + logf(s));
    float delta = fabsf(an - a[row]);
    a[row] = an;
    err_rows[row] = delta;
  }
}

// ---------------------------------------------------------------------------
// V partials: single-pass online (max,sum) over a 16-row chunk, all 1024 cols.
// Grid NB*NCHUNK = 1024 blocks; lane owns 4 consecutive cols (float4, coalesced).
// ---------------------------------------------------------------------------
__global__ __launch_bounds__(256) void v_partial(
    const float* __restrict__ Cs, const float* __restrict__ a,
    float* __restrict__ pm, float* __restrict__ ps,
    const int* __restrict__ doneArr, int it)
{
  if (doneArr[it]) return;
  const int n  = blockIdx.x >> 6;
  const int rc = blockIdx.x & (NCHUNK - 1);
  const int j0 = threadIdx.x * 4;
  const float* cb = Cs + ((size_t)n * PP + rc * RCHUNK) * PP + j0;
  const float* an = a + n * PP + rc * RCHUNK;

  float m0 = -INFINITY, m1 = -INFINITY, m2 = -INFINITY, m3 = -INFINITY;
  float s0 = 0.f, s1 = 0.f, s2 = 0.f, s3 = 0.f;
  #pragma unroll
  for (int r = 0; r < RCHUNK; ++r) {
    float ar = an[r];                       // uniform -> scalar load
    float4 c4 = *(const float4*)(cb + (size_t)r * PP);
    float t, mn;
    t = ar - c4.x; mn = fmaxf(m0, t); s0 = fmaf(s0, exp2f((m0-mn)*LOG2E), exp2f((t-mn)*LOG2E)); m0 = mn;
    t = ar - c4.y; mn = fmaxf(m1, t); s1 = fmaf(s1, exp2f((m1-mn)*LOG2E), exp2f((t-mn)*LOG2E)); m1 = mn;
    t = ar - c4.z; mn = fmaxf(m2, t); s2 = fmaf(s2, exp2f((m2-mn)*LOG2E), exp2f((t-mn)*LOG2E)); m2 = mn;
    t = ar - c4.w; mn = fmaxf(m3, t); s3 = fmaf(s3, exp2f((m3-mn)*LOG2E), exp2f((t-mn)*LOG2E)); m3 = mn;
  }
  size_t off = ((size_t)n * NCHUNK + rc) * PP + j0;
  *(float4*)(pm + off) = make_float4(m0, m1, m2, m3);
  *(float4*)(ps + off) = make_float4(s0, s1, s2, s3);
}

// ---------------------------------------------------------------------------
// V combine: merge NCHUNK partials per column -> b_j; block 0 also reduces
// err_rows (fixed order, deterministic) -> doneArr[it+1].
// Grid = NB*PP/256 = 64 blocks.
// ---------------------------------------------------------------------------
__global__ __launch_bounds__(256) void v_combine(
    const float* __restrict__ pm, const float* __restrict__ ps,
    float* __restrict__ b, const float* __restrict__ err_rows,
    int* __restrict__ doneArr, int it)
{
  if (doneArr[it]) {
    if (blockIdx.x == 0 && threadIdx.x == 0) doneArr[it + 1] = 1;
    return;
  }
  const int col = blockIdx.x * 256 + threadIdx.x;   // 0..16383
  const int n = col >> 10, j = col & (PP - 1);
  const float* pmn = pm + (size_t)n * NCHUNK * PP + j;
  const float* psn = ps + (size_t)n * NCHUNK * PP + j;

  float m = -INFINITY, s = 0.f;
  #pragma unroll 8
  for (int c = 0; c < NCHUNK; ++c) {
    float mc = pmn[(size_t)c * PP];
    float sc = psn[(size_t)c * PP];
    float mn = fmaxf(m, mc);
    s = fmaf(s, exp2f((m - mn) * LOG2E), sc * exp2f((mc - mn) * LOG2E));
    m = mn;
  }
  b[col] = LOG_MU - (m + logf(s));

  if (blockIdx.x == 0) {
    __shared__ float red[4];
    float loc = 0.f;
    for (int t = threadIdx.x; t < NB * PP; t += 256) loc += err_rows[t];
    #pragma unroll
    for (int off = 32; off > 0; off >>= 1) loc += __shfl_xor(loc, off);
    if ((threadIdx.x & 63) == 0) red[threadIdx.x >> 6] = loc;
    __syncthreads();
    if (threadIdx.x == 0) {
      float tot = red[0] + red[1] + red[2] + red[3];
      float err = tot * (EPSV / (float)NB);
      doneArr[it + 1] = (err < THRESHV) ? 1 : 0;
    }
  }
}

// ---------------------------------------------------------------------------
// pi = exp(a_i + b_j - Cs_ij), in place over Cs (d_out).
// ---------------------------------------------------------------------------
__global__ __launch_bounds__(256) void pi_kernel(
    float* __restrict__ Cs, const float* __restrict__ a, const float* __restrict__ b)
{
  const int lane = threadIdx.x & 63;
  const int row  = (blockIdx.x << 2) + (threadIdx.x >> 6);
  const int n    = row >> 10;
  const float ai = a[row];
  float* crow = Cs + (size_t)row * PP;
  const float* bn = b + n * PP;
  #pragma unroll
  for (int kk = 0; kk < 4; ++kk) {
    float4 c4 = *(const float4*)(crow + lane * 4 + kk * 256);
    float4 b4 = *(const float4*)(bn   + lane * 4 + kk * 256);
    float4 r;
    r.x = exp2f((ai + b4.x - c4.x) * LOG2E);
    r.y = exp2f((ai + b4.y - c4.y) * LOG2E);
    r.z = exp2f((ai + b4.z - c4.z) * LOG2E);
    r.w = exp2f((ai + b4.w - c4.w) * LOG2E);
    *(float4*)(crow + lane * 4 + kk * 256) = r;
  }
}

extern "C" void kernel_launch(void* const* d_in, const int* in_sizes, int n_in,
                              void* d_out, int out_size, void* d_ws, size_t ws_size,
                              hipStream_t stream)
{
  const float* y = (const float*)d_in[0];   // setup_inputs order: y first
  const float* x = (const float*)d_in[1];

  float* Cs       = (float*)d_out;                 // 16M floats
  float* a        = (float*)d_ws;                  // 16K
  float* b        = a + NB * PP;                   // 16K
  float* err_rows = b + NB * PP;                   // 16K
  int*   doneArr  = (int*)(err_rows + NB * PP);    // 16
  float* pm       = (float*)(doneArr + 16);        // NB*NCHUNK*PP = 1M floats
  float* ps       = pm + (size_t)NB * NCHUNK * PP; // 1M floats

  compute_c<<<NB * 16 * 8, 256, 0, stream>>>(x, y, Cs, a, b, doneArr);
  for (int it = 0; it < MAX_ITER; ++it) {
    u_kernel <<<NB * PP / 4,  256, 0, stream>>>(Cs, a, b, err_rows, doneArr, it);
    v_partial<<<NB * NCHUNK,  256, 0, stream>>>(Cs, a, pm, ps, doneArr, it);
    v_combine<<<NB * PP / 256, 256, 0, stream>>>(pm, ps, b, err_rows, doneArr, it);
  }
  pi_kernel<<<NB * PP / 4, 256, 0, stream>>>(Cs, a, b);
}